// Round 1
// baseline (2368.545 us; speedup 1.0000x reference)
//
#include <hip/hip_runtime.h>
#include <hip/hip_bf16.h>
#include <math.h>

// ---------------------------------------------------------------------------
// EntityMoELayer: pooling -> MoE(top2 of 8, GATHERED routing) -> self-attn -> FFN
// Round 3: sparse MoE dispatch. gate_kernel builds per-expert token lists
// (atomicAdd append); expert GEMMs run only over gathered rows (~2048/expert
// expected vs 8192 dense) -> 4x fewer MoE FLOPs, bitwise-identical result
// (dropped terms were exact *0.0f). GEMM1 gathers A rows via per-lane global
// addresses into global_load_lds (legal: global src is per-lane, LDS dest
// stays wave-uniform linear, m104/m108/m173). GEMM2 scatter-accumulates the
// epilogue to moeacc[token] guarded by row<cnt. Blocks past cnt early-exit.
// ---------------------------------------------------------------------------

typedef __bf16 bf16_t;
typedef __bf16 bf16x8 __attribute__((ext_vector_type(8)));
typedef float  f32x4  __attribute__((ext_vector_type(4)));

#define B_   8
#define NE_  1024
#define NO_  8
#define D_   1024
#define E_   8
#define H_   2048
#define O_   1024
#define NH_  8
#define HD_  128
#define FH_  4096
#define T_   8192   // B*NE tokens

__device__ __forceinline__ void gl2lds16(const bf16_t* g, bf16_t* l) {
    __builtin_amdgcn_global_load_lds(
        (const __attribute__((address_space(1))) unsigned int*)g,
        (__attribute__((address_space(3))) unsigned int*)l,
        16, 0, 0);
}

// ---------------------------------------------------------------------------
// Generic NT GEMM: C[M,N] = epi( A[M,K] * B[N,K]^T ), bf16 in, fp32 accum.
// 128x128 block tile, 4 waves (2x2 of 64x64), MFMA 16x16x32 bf16, BK=32.
// Staging: async global->LDS, 4 issues/thread/K-step (2 A + 2 B), each wave
// issue fills 16 rows (64B/row) at wave-uniform LDS base + lane*16.
// Batch (grid.z): bh = zbase+z, b=bh>>3, h=bh&7; per-operand offset
//   = b*s?b + h*s?h + z*s?z  (covers head-sliced Q/K/ctx and chunked S).
// GATHER: A row r comes from rowidx[r] (slots >= cnt read token 0, harmless;
//   their outputs are only consumed by rows the SCATTER pass guards off).
// SCATTER: C row = rowidx[r], epilogue skipped for r >= cnt (padded slots).
// Both early-exit whole blocks when rowBase >= cnt[expert].
// ---------------------------------------------------------------------------
template<typename OUT_T, bool TRANSC, bool BIAS, bool RELU, bool WSCALE,
         bool ACCUM, bool GATHER, bool SCATTER>
__global__ __launch_bounds__(256, 2)
void gemm_nt(const bf16_t* __restrict__ A, const bf16_t* __restrict__ Bm,
             OUT_T* __restrict__ C,
             const float* __restrict__ bias, const float* __restrict__ wfull, int expert,
             const int* __restrict__ rowidx, const int* __restrict__ cntp,
             int K, int lda, int ldb, int ldc, float alpha, int zbase,
             long sAb, long sAh, long sAz,
             long sBb, long sBh, long sBz,
             long sCb, long sCh, long sCz)
{
    const int z  = blockIdx.z;
    const long bh = zbase + z;
    const long bb = bh >> 3, hh = bh & 7;
    A  += bb*sAb + hh*sAh + (long)z*sAz;
    Bm += bb*sBb + hh*sBh + (long)z*sBz;
    C  += bb*sCb + hh*sCh + (long)z*sCz;

    const int rowBase = blockIdx.x * 128;
    const int colBase = blockIdx.y * 128;

    int cnt = 0;
    if (GATHER || SCATTER) {
        cnt = cntp[expert];
        if (rowBase >= cnt) return;   // uniform: whole block pads -> skip
    }

    __shared__ __align__(16) bf16_t As[128*32];
    __shared__ __align__(16) bf16_t Bs[128*32];

    const int t    = threadIdx.x;
    const int lane = t & 63, wave = t >> 6;
    const int l16  = lane & 15, quad = lane >> 4;
    const int wm   = (wave & 1) * 64, wn = (wave >> 1) * 64;

    // async staging source: issue j covers rows [j*64 + wave*16, +16);
    // lane -> row += lane/4, 16B chunk = lane%4. LDS dest wave-uniform.
    const int lrow = lane >> 2;
    const int lch  = (lane & 3) * 8;          // halves
    long arow0 = rowBase + wave*16 + lrow;
    long arow1 = arow0 + 64;
    if (GATHER) {
        const int s0 = rowBase + wave*16 + lrow;
        const int s1 = s0 + 64;
        arow0 = (s0 < cnt) ? (long)rowidx[s0] : 0;
        arow1 = (s1 < cnt) ? (long)rowidx[s1] : 0;
    }
    const bf16_t* agp0 = A  + arow0*lda + lch;
    const bf16_t* agp1 = A  + arow1*lda + lch;
    const bf16_t* bgp0 = Bm + (long)(colBase + wave*16 + lrow)*ldb + lch;
    const bf16_t* bgp1 = bgp0 + (long)64*ldb;
    bf16_t* alp0 = &As[wave*512];             // 512 halves = 16 rows
    bf16_t* alp1 = &As[(4 + wave)*512];
    bf16_t* blp0 = &Bs[wave*512];
    bf16_t* blp1 = &Bs[(4 + wave)*512];

    f32x4 acc[4][4] = {};

    for (int k0 = 0; k0 < K; k0 += 32) {
        __syncthreads();                      // prev iter's ds_reads done
        gl2lds16(agp0 + k0, alp0);
        gl2lds16(agp1 + k0, alp1);
        gl2lds16(bgp0 + k0, blp0);
        gl2lds16(bgp1 + k0, blp1);
        __syncthreads();                      // vmcnt(0) drain + barrier

        bf16x8 af[4], bfr[4];
        #pragma unroll
        for (int mi = 0; mi < 4; mi++)
            af[mi] = *(const bf16x8*)&As[(wm + mi*16 + l16)*32 + quad*8];
        #pragma unroll
        for (int ni = 0; ni < 4; ni++)
            bfr[ni] = *(const bf16x8*)&Bs[(wn + ni*16 + l16)*32 + quad*8];
        #pragma unroll
        for (int mi = 0; mi < 4; mi++)
            #pragma unroll
            for (int ni = 0; ni < 4; ni++)
                acc[mi][ni] = __builtin_amdgcn_mfma_f32_16x16x32_bf16(
                                  af[mi], bfr[ni], acc[mi][ni], 0, 0, 0);
    }

    // epilogue: D[row = quad*4+r][col = l16] per 16x16 tile (m89-verified map)
    #pragma unroll
    for (int mi = 0; mi < 4; mi++) {
        #pragma unroll
        for (int ni = 0; ni < 4; ni++) {
            const int col = colBase + wn + ni*16 + l16;
            float bv = 0.0f;
            if (BIAS) bv = bias[col];
            #pragma unroll
            for (int rr = 0; rr < 4; rr++) {
                const int row = rowBase + wm + mi*16 + quad*4 + rr;
                if (SCATTER && row >= cnt) continue;   // padded slot: no write
                long crow = row;
                if (SCATTER) crow = (long)rowidx[row];
                float v = acc[mi][ni][rr] * alpha;
                if (BIAS)   v += bv;
                if (RELU)   v = fmaxf(v, 0.0f);
                if (WSCALE) v *= wfull[crow*8 + expert];
                if (ACCUM) {
                    C[crow*ldc + col] += v;           // fp32 accum buffer
                } else if (TRANSC) {
                    C[(long)col*ldc + crow] = (OUT_T)v; // write C^T (for V)
                } else {
                    C[crow*ldc + col] = (OUT_T)v;
                }
            }
        }
    }
}

// ---------------------------------------------------------------------------
// fp32 (R x C) -> bf16 transposed (C x R), 64x64 LDS tiles, batched (grid.z)
// ---------------------------------------------------------------------------
__global__ __launch_bounds__(256)
void transpose_convert(const float* __restrict__ in, bf16_t* __restrict__ out,
                       int R, int C, long inStride, long outStride)
{
    __shared__ float tl[64][65];
    const int t = threadIdx.x;
    const float* src = in  + (long)blockIdx.z * inStride;
    bf16_t*      dst = out + (long)blockIdx.z * outStride;
    const int c0 = blockIdx.x * 64, r0 = blockIdx.y * 64;
    #pragma unroll
    for (int i = 0; i < 16; i++) {
        const int idx = t + i*256, r = idx >> 6, c = idx & 63;
        tl[r][c] = src[(long)(r0 + r)*C + c0 + c];
    }
    __syncthreads();
    #pragma unroll
    for (int i = 0; i < 16; i++) {
        const int idx = t + i*256, rT = idx >> 6, cT = idx & 63;
        dst[(long)(c0 + rT)*R + r0 + cT] = (bf16_t)tl[cT][rT];
    }
}

// ---------------------------------------------------------------------------
// Entity pooling: per token (b,n): softmax over NO=8 object logits (x.attn_w),
// weighted sum over objects -> x_agg (fp32 + bf16). One block per token.
// ---------------------------------------------------------------------------
__global__ __launch_bounds__(256)
void pool_kernel(const float* __restrict__ x, const float* __restrict__ attn_w,
                 float* __restrict__ xaggf, bf16_t* __restrict__ xaggb)
{
    __shared__ float xs[8192];      // 8 objects x 1024 dims
    __shared__ float red[32];
    const int t = threadIdx.x;
    const long tok = blockIdx.x;
    const float4* src = (const float4*)(x + tok*8192);
    float4* xs4 = (float4*)xs;
    #pragma unroll
    for (int i = 0; i < 8; i++) xs4[t + i*256] = src[t + i*256];
    float wreg[4];
    #pragma unroll
    for (int j = 0; j < 4; j++) wreg[j] = attn_w[t + j*256];
    __syncthreads();

    float part[8];
    #pragma unroll
    for (int o = 0; o < 8; o++) {
        float p = 0.0f;
        #pragma unroll
        for (int j = 0; j < 4; j++) p += xs[o*1024 + t + j*256] * wreg[j];
        part[o] = p;
    }
    const int lane = t & 63, wv = t >> 6;
    #pragma unroll
    for (int o = 0; o < 8; o++) {
        float v = part[o];
        for (int off = 32; off; off >>= 1) v += __shfl_down(v, off);
        if (lane == 0) red[o*4 + wv] = v;
    }
    __syncthreads();
    float lg[8], mx = -3.4e38f;
    #pragma unroll
    for (int o = 0; o < 8; o++) {
        lg[o] = red[o*4] + red[o*4+1] + red[o*4+2] + red[o*4+3];
        mx = fmaxf(mx, lg[o]);
    }
    float ssum = 0.0f;
    #pragma unroll
    for (int o = 0; o < 8; o++) { lg[o] = expf(lg[o] - mx); ssum += lg[o]; }
    const float inv = 1.0f / ssum;
    #pragma unroll
    for (int j = 0; j < 4; j++) {
        const int d = t + j*256;
        float a = 0.0f;
        #pragma unroll
        for (int o = 0; o < 8; o++) a += lg[o] * xs[o*1024 + d];
        a *= inv;
        xaggf[tok*1024 + d] = a;
        xaggb[tok*1024 + d] = (bf16_t)a;
    }
}

// ---------------------------------------------------------------------------
// Gate: fp32 logits (xagg @ gate_W + b), softmax, top-2 (tie -> lower index,
// matches lax.top_k), renormalized gates scattered into dense wfull[T,8].
// Also appends the token to its two experts' gather lists (atomicAdd).
// One wave per token.
// ---------------------------------------------------------------------------
__global__ __launch_bounds__(256)
void gate_kernel(const float* __restrict__ xaggf, const float* __restrict__ gate_W,
                 const float* __restrict__ gate_b, float* __restrict__ wfull,
                 int* __restrict__ ecnt, int* __restrict__ eidx)
{
    const int t = threadIdx.x;
    const int lane = t & 63, wv = t >> 6;
    const long tok = (long)blockIdx.x*4 + wv;
    const float* xr = xaggf + tok*1024;
    float acc[8] = {0,0,0,0,0,0,0,0};
    for (int j = 0; j < 16; j++) {
        const int d = lane + j*64;
        const float xv = xr[d];
        const float4 w0 = *(const float4*)(gate_W + (long)d*8);
        const float4 w1 = *(const float4*)(gate_W + (long)d*8 + 4);
        acc[0] += xv*w0.x; acc[1] += xv*w0.y; acc[2] += xv*w0.z; acc[3] += xv*w0.w;
        acc[4] += xv*w1.x; acc[5] += xv*w1.y; acc[6] += xv*w1.z; acc[7] += xv*w1.w;
    }
    #pragma unroll
    for (int e = 0; e < 8; e++)
        for (int off = 32; off; off >>= 1) acc[e] += __shfl_down(acc[e], off);
    if (lane == 0) {
        float l[8];
        #pragma unroll
        for (int e = 0; e < 8; e++) l[e] = acc[e] + gate_b[e];
        int i1 = 0; float v1 = l[0];
        #pragma unroll
        for (int e = 1; e < 8; e++) if (l[e] > v1) { v1 = l[e]; i1 = e; }
        int i2 = -1; float v2 = -3.4e38f;
        #pragma unroll
        for (int e = 0; e < 8; e++) if (e != i1 && l[e] > v2) { v2 = l[e]; i2 = e; }
        // renormalized top-2 softmax gates (Z cancels): g1 = 1/(1+e^{l2-l1})
        const float tt = expf(v2 - v1);
        const float g1 = 1.0f/(1.0f + tt), g2 = tt/(1.0f + tt);
        float* wo = wfull + tok*8;
        #pragma unroll
        for (int e = 0; e < 8; e++) wo[e] = 0.0f;
        wo[i1] = g1; wo[i2] = g2;
        // gather lists (order within an expert is irrelevant: per-token math
        // and the expert-ordered accumulation into moeacc are unchanged)
        const int s1 = atomicAdd(&ecnt[i1], 1); eidx[i1*T_ + s1] = (int)tok;
        const int s2 = atomicAdd(&ecnt[i2], 1); eidx[i2*T_ + s2] = (int)tok;
    }
}

// ---------------------------------------------------------------------------
// Row softmax over 1024 fp32 scores; writes bf16 probs in-place into the
// first half of each row (row stride stays 1024 floats -> P lda = 2048 bf16).
// One block per row.
// ---------------------------------------------------------------------------
__global__ __launch_bounds__(256)
void softmax_rows(float* __restrict__ S)
{
    __shared__ float redA[4], redB[4];
    const int t = threadIdx.x;
    float* rowp = S + (long)blockIdx.x * 1024;
    const float4 v = ((const float4*)rowp)[t];
    const int lane = t & 63, wv = t >> 6;
    float m = fmaxf(fmaxf(v.x, v.y), fmaxf(v.z, v.w));
    for (int off = 32; off; off >>= 1) m = fmaxf(m, __shfl_down(m, off));
    if (lane == 0) redA[wv] = m;
    __syncthreads();
    m = fmaxf(fmaxf(redA[0], redA[1]), fmaxf(redA[2], redA[3]));
    const float e0 = expf(v.x - m), e1 = expf(v.y - m);
    const float e2 = expf(v.z - m), e3 = expf(v.w - m);
    float s = e0 + e1 + e2 + e3;
    for (int off = 32; off; off >>= 1) s += __shfl_down(s, off);
    if (lane == 0) redB[wv] = s;
    __syncthreads();
    const float inv = 1.0f / (redB[0] + redB[1] + redB[2] + redB[3]);
    union { bf16_t h[4]; uint2 u; } pk;
    pk.h[0] = (bf16_t)(e0*inv); pk.h[1] = (bf16_t)(e1*inv);
    pk.h[2] = (bf16_t)(e2*inv); pk.h[3] = (bf16_t)(e3*inv);
    ((uint2*)rowp)[t] = pk.u;
}

// fp32 -> bf16 elementwise (ent conversion)
__global__ __launch_bounds__(256)
void f2b_kernel(const float* __restrict__ in, bf16_t* __restrict__ out)
{
    const long i = ((long)blockIdx.x*256 + threadIdx.x) * 4;
    const float4 v = *(const float4*)(in + i);
    union { bf16_t h[4]; uint2 u; } pk;
    pk.h[0] = (bf16_t)v.x; pk.h[1] = (bf16_t)v.y;
    pk.h[2] = (bf16_t)v.z; pk.h[3] = (bf16_t)v.w;
    *(uint2*)(out + i) = pk.u;
}

// ---------------------------------------------------------------------------
extern "C" void kernel_launch(void* const* d_in, const int* in_sizes, int n_in,
                              void* d_out, int out_size, void* d_ws, size_t ws_size,
                              hipStream_t stream)
{
    const float* x      = (const float*)d_in[0];
    const float* attn_w = (const float*)d_in[1];
    const float* gate_W = (const float*)d_in[2];
    const float* gate_b = (const float*)d_in[3];
    const float* eW1    = (const float*)d_in[4];
    const float* eb1    = (const float*)d_in[5];
    const float* eW2    = (const float*)d_in[6];
    const float* eb2    = (const float*)d_in[7];
    const float* Wq     = (const float*)d_in[8];   const float* bq = (const float*)d_in[9];
    const float* Wk     = (const float*)d_in[10];  const float* bk = (const float*)d_in[11];
    const float* Wv     = (const float*)d_in[12];  const float* bv = (const float*)d_in[13];
    const float* Wo     = (const float*)d_in[14];  const float* bo = (const float*)d_in[15];
    const float* fW1    = (const float*)d_in[16];  const float* fb1 = (const float*)d_in[17];
    const float* fW2    = (const float*)d_in[18];  const float* fb2 = (const float*)d_in[19];
    float* out = (float*)d_out;

    char* ws = (char*)d_ws;
    size_t off = 0;
    auto alloc = [&](size_t sz) -> void* {
        void* p = (void*)(ws + off);
        off += (sz + 255) & ~(size_t)255;
        return p;
    };
    // bf16 transposed weights + routing tables (persist whole call)
    bf16_t* WqT  = (bf16_t*)alloc((size_t)O_*O_*2);
    bf16_t* WkT  = (bf16_t*)alloc((size_t)O_*O_*2);
    bf16_t* WvT  = (bf16_t*)alloc((size_t)O_*O_*2);
    bf16_t* WoT  = (bf16_t*)alloc((size_t)O_*O_*2);
    bf16_t* fW1T = (bf16_t*)alloc((size_t)O_*FH_*2);
    bf16_t* fW2T = (bf16_t*)alloc((size_t)FH_*O_*2);
    bf16_t* eW1T = (bf16_t*)alloc((size_t)E_*D_*H_*2);
    bf16_t* eW2T = (bf16_t*)alloc((size_t)E_*H_*O_*2);
    int*    ecnt = (int*)alloc((size_t)E_*4);
    int*    eidx = (int*)alloc((size_t)E_*T_*4);
    const size_t reuse0 = off;                         // ffn_h aliases from here
    float*  xaggf  = (float*)alloc((size_t)T_*D_*4);
    bf16_t* xaggb  = (bf16_t*)alloc((size_t)T_*D_*2);
    float*  wfull  = (float*)alloc((size_t)T_*E_*4);
    bf16_t* hidden = (bf16_t*)alloc((size_t)T_*H_*2);
    float*  moeacc = (float*)alloc((size_t)T_*O_*4);
    bf16_t* entb   = (bf16_t*)alloc((size_t)T_*O_*2);
    bf16_t* qb     = (bf16_t*)alloc((size_t)T_*O_*2);
    bf16_t* kb     = (bf16_t*)alloc((size_t)T_*O_*2);
    bf16_t* vT     = (bf16_t*)alloc((size_t)O_*T_*2); // V^T: (channel, token)
    float*  S      = (float*)alloc((size_t)16*NE_*NE_*4); // 16-bh score chunk
    bf16_t* ctxb   = (bf16_t*)alloc((size_t)T_*O_*2);
    // aliases (regions dead by the time these are written):
    bf16_t* ffnhb  = (bf16_t*)(ws + reuse0);          // over xaggf..hidden (80MB>64MB)
    bf16_t* relb   = (bf16_t*)moeacc;                 // over moeacc (33MB>16MB)

    const dim3 blk(256);

    // 1) weights -> bf16, transposed (all GEMMs become NT)
    transpose_convert<<<dim3(H_/64, D_/64, E_), blk, 0, stream>>>(eW1, eW1T, D_, H_, (long)D_*H_, (long)D_*H_);
    transpose_convert<<<dim3(O_/64, H_/64, E_), blk, 0, stream>>>(eW2, eW2T, H_, O_, (long)H_*O_, (long)H_*O_);
    transpose_convert<<<dim3(O_/64, O_/64, 1), blk, 0, stream>>>(Wq, WqT, O_, O_, 0, 0);
    transpose_convert<<<dim3(O_/64, O_/64, 1), blk, 0, stream>>>(Wk, WkT, O_, O_, 0, 0);
    transpose_convert<<<dim3(O_/64, O_/64, 1), blk, 0, stream>>>(Wv, WvT, O_, O_, 0, 0);
    transpose_convert<<<dim3(O_/64, O_/64, 1), blk, 0, stream>>>(Wo, WoT, O_, O_, 0, 0);
    transpose_convert<<<dim3(FH_/64, O_/64, 1), blk, 0, stream>>>(fW1, fW1T, O_, FH_, 0, 0);
    transpose_convert<<<dim3(O_/64, FH_/64, 1), blk, 0, stream>>>(fW2, fW2T, FH_, O_, 0, 0);

    // 2) pooling + gating (gate also builds the per-expert gather lists)
    (void)hipMemsetAsync(ecnt, 0, (size_t)E_*4, stream);
    pool_kernel<<<dim3(T_), blk, 0, stream>>>(x, attn_w, xaggf, xaggb);
    gate_kernel<<<dim3(T_/4), blk, 0, stream>>>(xaggf, gate_W, gate_b, wfull, ecnt, eidx);

    // 3) MoE, sparse: per expert, GEMMs over only its gathered tokens.
    //    Grid worst-case-sized (64 row-blocks); blocks past cnt[e] early-exit.
    (void)hipMemsetAsync(moeacc, 0, (size_t)T_*O_*4, stream);
    for (int e = 0; e < E_; e++) {
        // hidden[slot] = relu(xagg[idx[slot]] @ W1e + b1e)   (gathered A)
        gemm_nt<bf16_t, false, true, true, false, false, true, false><<<dim3(64, 16, 1), blk, 0, stream>>>(
            xaggb, eW1T + (size_t)e*D_*H_, hidden, eb1 + (size_t)e*H_, nullptr, e,
            eidx + (size_t)e*T_, ecnt,
            D_, D_, D_, H_, 1.0f, 0, 0,0,0, 0,0,0, 0,0,0);
        // moeacc[idx[slot]] += gate * (hidden[slot] @ W2e + b2e)  (scattered C)
        gemm_nt<float, false, true, false, true, true, false, true><<<dim3(64, 8, 1), blk, 0, stream>>>(
            hidden, eW2T + (size_t)e*H_*O_, moeacc, eb2 + (size_t)e*O_, wfull, e,
            eidx + (size_t)e*T_, ecnt,
            H_, H_, H_, O_, 1.0f, 0, 0,0,0, 0,0,0, 0,0,0);
    }
    f2b_kernel<<<dim3(T_*O_/1024), blk, 0, stream>>>(moeacc, entb);

    // 4) QKV projections (V written transposed as (channel, token))
    gemm_nt<bf16_t, false, true, false, false, false, false, false><<<dim3(64, 8, 1), blk, 0, stream>>>(
        entb, WqT, qb, bq, nullptr, 0, nullptr, nullptr, O_, O_, O_, O_, 1.0f, 0, 0,0,0, 0,0,0, 0,0,0);
    gemm_nt<bf16_t, false, true, false, false, false, false, false><<<dim3(64, 8, 1), blk, 0, stream>>>(
        entb, WkT, kb, bk, nullptr, 0, nullptr, nullptr, O_, O_, O_, O_, 1.0f, 0, 0,0,0, 0,0,0, 0,0,0);
    gemm_nt<bf16_t, true, true, false, false, false, false, false><<<dim3(64, 8, 1), blk, 0, stream>>>(
        entb, WvT, vT, bv, nullptr, 0, nullptr, nullptr, O_, O_, O_, T_, 1.0f, 0, 0,0,0, 0,0,0, 0,0,0);

    // 5) attention, 4 chunks of 16 (b,h) slabs
    const float scl = 0.088388347648318447f;  // 1/sqrt(128)
    for (int c = 0; c < 4; c++) {
        const int zb = c * 16;
        // S = scl * Q K^T   (fp32 out)
        gemm_nt<float, false, false, false, false, false, false, false><<<dim3(8, 8, 16), blk, 0, stream>>>(
            qb, kb, S, nullptr, nullptr, 0, nullptr, nullptr, HD_, O_, O_, NE_, scl, zb,
            (long)NE_*O_, HD_, 0,   (long)NE_*O_, HD_, 0,   0, 0, (long)NE_*NE_);
        softmax_rows<<<dim3(16*NE_), blk, 0, stream>>>(S);
        // ctx = P V   (P bf16 in-place in S rows, lda=2048)
        gemm_nt<bf16_t, false, false, false, false, false, false, false><<<dim3(8, 1, 16), blk, 0, stream>>>(
            (const bf16_t*)S, vT, ctxb, nullptr, nullptr, 0, nullptr, nullptr, NE_, 2*NE_, T_, O_, 1.0f, zb,
            0, 0, (long)2*NE_*NE_,   (long)NE_, (long)HD_*T_, 0,   (long)NE_*O_, HD_, 0);
    }

    // 6) output projection + FFN
    gemm_nt<bf16_t, false, true, false, false, false, false, false><<<dim3(64, 8, 1), blk, 0, stream>>>(
        ctxb, WoT, relb, bo, nullptr, 0, nullptr, nullptr, O_, O_, O_, O_, 1.0f, 0, 0,0,0, 0,0,0, 0,0,0);
    gemm_nt<bf16_t, false, true, true, false, false, false, false><<<dim3(64, 32, 1), blk, 0, stream>>>(
        relb, fW1T, ffnhb, fb1, nullptr, 0, nullptr, nullptr, O_, O_, O_, FH_, 1.0f, 0, 0,0,0, 0,0,0, 0,0,0);
    gemm_nt<float, false, true, false, false, false, false, false><<<dim3(64, 8, 1), blk, 0, stream>>>(
        ffnhb, fW2T, out, fb2, nullptr, 0, nullptr, nullptr, FH_, FH_, FH_, O_, 1.0f, 0, 0,0,0, 0,0,0, 0,0,0);
}

// Round 2
// 1373.212 us; speedup vs baseline: 1.7248x; 1.7248x over previous
//
#include <hip/hip_runtime.h>
#include <hip/hip_bf16.h>
#include <math.h>

// ---------------------------------------------------------------------------
// EntityMoELayer: pooling -> MoE(top2 of 8, GROUPED sparse GEMM) -> attn -> FFN
// Round 4: fixes round-3's two regressions:
//  (1) gate_kernel atomic storm (16384 same-cache-line device atomics ~200us)
//      -> routing rebuilt with LDS-only atomics (3 tiny kernels, deterministic).
//  (2) per-expert GEMM underutilization (128-256 blocks, 16 dependent
//      launches) -> ONE grouped GEMM per MoE layer over 128-aligned expert
//      slot segments (2176 / 1088 blocks, full machine).
// GEMM2 writes slot-major out2 (bias included); combine does
// ent[tok] = g1*out2[s1] + g2*out2[s2] (2-term fp add = commutative, bitwise
// identical to reference's expert-ordered accumulation).
// ---------------------------------------------------------------------------

typedef __bf16 bf16_t;
typedef __bf16 bf16x8 __attribute__((ext_vector_type(8)));
typedef float  f32x4  __attribute__((ext_vector_type(4)));

#define B_   8
#define NE_  1024
#define NO_  8
#define D_   1024
#define E_   8
#define H_   2048
#define O_   1024
#define NH_  8
#define HD_  128
#define FH_  4096
#define T_   8192          // B*NE tokens
#define NRB_ 32            // routing blocks (256 tokens each)
#define NBLK_ 136          // worst-case 128-row slot blocks (actual <= 135)
#define SLOTS_ (NBLK_*128) // 17408

__device__ __forceinline__ void gl2lds16(const bf16_t* g, bf16_t* l) {
    __builtin_amdgcn_global_load_lds(
        (const __attribute__((address_space(1))) unsigned int*)g,
        (__attribute__((address_space(3))) unsigned int*)l,
        16, 0, 0);
}

// ---------------------------------------------------------------------------
// Generic NT GEMM: C[M,N] = epi( A[M,K] * B[N,K]^T ), bf16 in, fp32 accum.
// 128x128 block tile, 4 waves (2x2 of 64x64), MFMA 16x16x32 bf16, BK=32.
// Staging: async global->LDS, 4 issues/thread/K-step (2 A + 2 B), each wave
// issue fills 16 rows (64B/row) at wave-uniform LDS base + lane*16.
// Batch (grid.z): bh = zbase+z, b=bh>>3, h=bh&7 (head-sliced Q/K/ctx, chunked S).
// GROUPED: row-block -> expert via blkexp[] (-1 = unused tail, early exit);
//   B and bias offset by expert. Segments are 128-aligned so every active
//   block is full (no partial-row guards needed).
// GATHER: A row = rowidx[slot] (pad slots pre-zeroed -> token 0, harmless;
//   per-lane global src addresses are legal for global_load_lds, m173).
// ---------------------------------------------------------------------------
template<typename OUT_T, bool TRANSC, bool BIAS, bool RELU, bool GROUPED, bool GATHER>
__global__ __launch_bounds__(256, 2)
void gemm_nt(const bf16_t* __restrict__ A, const bf16_t* __restrict__ Bm,
             OUT_T* __restrict__ C,
             const float* __restrict__ bias,
             const int* __restrict__ rowidx, const int* __restrict__ blkexp,
             int K, int lda, int ldb, int ldc, float alpha, int zbase,
             long sBe, int biasStride,
             long sAb, long sAh, long sAz,
             long sBb, long sBh, long sBz,
             long sCb, long sCh, long sCz)
{
    const int z  = blockIdx.z;
    const long bh = zbase + z;
    const long bb = bh >> 3, hh = bh & 7;
    A  += bb*sAb + hh*sAh + (long)z*sAz;
    Bm += bb*sBb + hh*sBh + (long)z*sBz;
    C  += bb*sCb + hh*sCh + (long)z*sCz;

    if (GROUPED) {
        const int ge = blkexp[blockIdx.x];
        if (ge < 0) return;               // uniform early exit (tail blocks)
        Bm += (long)ge * sBe;
        if (BIAS) bias += (long)ge * biasStride;
    }

    __shared__ __align__(16) bf16_t As[128*32];
    __shared__ __align__(16) bf16_t Bs[128*32];

    const int t    = threadIdx.x;
    const int lane = t & 63, wave = t >> 6;
    const int l16  = lane & 15, quad = lane >> 4;
    const int wm   = (wave & 1) * 64, wn = (wave >> 1) * 64;
    const int rowBase = blockIdx.x * 128;
    const int colBase = blockIdx.y * 128;

    // async staging source: issue j covers rows [j*64 + wave*16, +16);
    // lane -> row += lane/4, 16B chunk = lane%4. LDS dest wave-uniform.
    const int lrow = lane >> 2;
    const int lch  = (lane & 3) * 8;          // halves
    long arow0, arow1;
    if (GATHER) {
        arow0 = rowidx[rowBase + wave*16 + lrow];
        arow1 = rowidx[rowBase + wave*16 + lrow + 64];
    } else {
        arow0 = rowBase + wave*16 + lrow;
        arow1 = arow0 + 64;
    }
    const bf16_t* agp0 = A  + arow0*lda + lch;
    const bf16_t* agp1 = A  + arow1*lda + lch;
    const bf16_t* bgp0 = Bm + (long)(colBase + wave*16 + lrow)*ldb + lch;
    const bf16_t* bgp1 = bgp0 + (long)64*ldb;
    bf16_t* alp0 = &As[wave*512];             // 512 halves = 16 rows
    bf16_t* alp1 = &As[(4 + wave)*512];
    bf16_t* blp0 = &Bs[wave*512];
    bf16_t* blp1 = &Bs[(4 + wave)*512];

    f32x4 acc[4][4] = {};

    for (int k0 = 0; k0 < K; k0 += 32) {
        __syncthreads();                      // prev iter's ds_reads done
        gl2lds16(agp0 + k0, alp0);
        gl2lds16(agp1 + k0, alp1);
        gl2lds16(bgp0 + k0, blp0);
        gl2lds16(bgp1 + k0, blp1);
        __syncthreads();                      // vmcnt(0) drain + barrier

        bf16x8 af[4], bfr[4];
        #pragma unroll
        for (int mi = 0; mi < 4; mi++)
            af[mi] = *(const bf16x8*)&As[(wm + mi*16 + l16)*32 + quad*8];
        #pragma unroll
        for (int ni = 0; ni < 4; ni++)
            bfr[ni] = *(const bf16x8*)&Bs[(wn + ni*16 + l16)*32 + quad*8];
        #pragma unroll
        for (int mi = 0; mi < 4; mi++)
            #pragma unroll
            for (int ni = 0; ni < 4; ni++)
                acc[mi][ni] = __builtin_amdgcn_mfma_f32_16x16x32_bf16(
                                  af[mi], bfr[ni], acc[mi][ni], 0, 0, 0);
    }

    // epilogue: D[row = quad*4+r][col = l16] per 16x16 tile (m89-verified map)
    #pragma unroll
    for (int mi = 0; mi < 4; mi++) {
        #pragma unroll
        for (int ni = 0; ni < 4; ni++) {
            const int col = colBase + wn + ni*16 + l16;
            float bv = 0.0f;
            if (BIAS) bv = bias[col];
            #pragma unroll
            for (int rr = 0; rr < 4; rr++) {
                const int row = rowBase + wm + mi*16 + quad*4 + rr;
                float v = acc[mi][ni][rr] * alpha;
                if (BIAS)   v += bv;
                if (RELU)   v = fmaxf(v, 0.0f);
                if (TRANSC) C[(long)col*ldc + row] = (OUT_T)v;  // C^T (for V)
                else        C[(long)row*ldc + col] = (OUT_T)v;
            }
        }
    }
}

// ---------------------------------------------------------------------------
// fp32 (R x C) -> bf16 transposed (C x R), 64x64 LDS tiles, batched (grid.z)
// ---------------------------------------------------------------------------
__global__ __launch_bounds__(256)
void transpose_convert(const float* __restrict__ in, bf16_t* __restrict__ out,
                       int R, int C, long inStride, long outStride)
{
    __shared__ float tl[64][65];
    const int t = threadIdx.x;
    const float* src = in  + (long)blockIdx.z * inStride;
    bf16_t*      dst = out + (long)blockIdx.z * outStride;
    const int c0 = blockIdx.x * 64, r0 = blockIdx.y * 64;
    #pragma unroll
    for (int i = 0; i < 16; i++) {
        const int idx = t + i*256, r = idx >> 6, c = idx & 63;
        tl[r][c] = src[(long)(r0 + r)*C + c0 + c];
    }
    __syncthreads();
    #pragma unroll
    for (int i = 0; i < 16; i++) {
        const int idx = t + i*256, rT = idx >> 6, cT = idx & 63;
        dst[(long)(c0 + rT)*R + r0 + cT] = (bf16_t)tl[cT][rT];
    }
}

// ---------------------------------------------------------------------------
// Entity pooling: per token (b,n): softmax over NO=8 object logits (x.attn_w),
// weighted sum over objects -> x_agg (fp32 + bf16). One block per token.
// ---------------------------------------------------------------------------
__global__ __launch_bounds__(256)
void pool_kernel(const float* __restrict__ x, const float* __restrict__ attn_w,
                 float* __restrict__ xaggf, bf16_t* __restrict__ xaggb)
{
    __shared__ float xs[8192];      // 8 objects x 1024 dims
    __shared__ float red[32];
    const int t = threadIdx.x;
    const long tok = blockIdx.x;
    const float4* src = (const float4*)(x + tok*8192);
    float4* xs4 = (float4*)xs;
    #pragma unroll
    for (int i = 0; i < 8; i++) xs4[t + i*256] = src[t + i*256];
    float wreg[4];
    #pragma unroll
    for (int j = 0; j < 4; j++) wreg[j] = attn_w[t + j*256];
    __syncthreads();

    float part[8];
    #pragma unroll
    for (int o = 0; o < 8; o++) {
        float p = 0.0f;
        #pragma unroll
        for (int j = 0; j < 4; j++) p += xs[o*1024 + t + j*256] * wreg[j];
        part[o] = p;
    }
    const int lane = t & 63, wv = t >> 6;
    #pragma unroll
    for (int o = 0; o < 8; o++) {
        float v = part[o];
        for (int off = 32; off; off >>= 1) v += __shfl_down(v, off);
        if (lane == 0) red[o*4 + wv] = v;
    }
    __syncthreads();
    float lg[8], mx = -3.4e38f;
    #pragma unroll
    for (int o = 0; o < 8; o++) {
        lg[o] = red[o*4] + red[o*4+1] + red[o*4+2] + red[o*4+3];
        mx = fmaxf(mx, lg[o]);
    }
    float ssum = 0.0f;
    #pragma unroll
    for (int o = 0; o < 8; o++) { lg[o] = expf(lg[o] - mx); ssum += lg[o]; }
    const float inv = 1.0f / ssum;
    #pragma unroll
    for (int j = 0; j < 4; j++) {
        const int d = t + j*256;
        float a = 0.0f;
        #pragma unroll
        for (int o = 0; o < 8; o++) a += lg[o] * xs[o*1024 + d];
        a *= inv;
        xaggf[tok*1024 + d] = a;
        xaggb[tok*1024 + d] = (bf16_t)a;
    }
}

// ---------------------------------------------------------------------------
// Gate: fp32 logits (xagg @ gate_W + b), top-2 (tie -> lower index, matches
// lax.top_k), renormalized gates. Writes ONLY per-token picks (2x3-bit expert
// ids) + gpair (g1,g2). NO global atomics (round-3's 200us stall).
// One wave per token.
// ---------------------------------------------------------------------------
__global__ __launch_bounds__(256)
void gate_kernel(const float* __restrict__ xaggf, const float* __restrict__ gate_W,
                 const float* __restrict__ gate_b, float* __restrict__ gpair,
                 unsigned int* __restrict__ picks)
{
    const int t = threadIdx.x;
    const int lane = t & 63, wv = t >> 6;
    const long tok = (long)blockIdx.x*4 + wv;
    const float* xr = xaggf + tok*1024;
    float acc[8] = {0,0,0,0,0,0,0,0};
    for (int j = 0; j < 16; j++) {
        const int d = lane + j*64;
        const float xv = xr[d];
        const float4 w0 = *(const float4*)(gate_W + (long)d*8);
        const float4 w1 = *(const float4*)(gate_W + (long)d*8 + 4);
        acc[0] += xv*w0.x; acc[1] += xv*w0.y; acc[2] += xv*w0.z; acc[3] += xv*w0.w;
        acc[4] += xv*w1.x; acc[5] += xv*w1.y; acc[6] += xv*w1.z; acc[7] += xv*w1.w;
    }
    #pragma unroll
    for (int e = 0; e < 8; e++)
        for (int off = 32; off; off >>= 1) acc[e] += __shfl_down(acc[e], off);
    if (lane == 0) {
        float l[8];
        #pragma unroll
        for (int e = 0; e < 8; e++) l[e] = acc[e] + gate_b[e];
        int i1 = 0; float v1 = l[0];
        #pragma unroll
        for (int e = 1; e < 8; e++) if (l[e] > v1) { v1 = l[e]; i1 = e; }
        int i2 = -1; float v2 = -3.4e38f;
        #pragma unroll
        for (int e = 0; e < 8; e++) if (e != i1 && l[e] > v2) { v2 = l[e]; i2 = e; }
        // renormalized top-2 softmax gates (Z cancels): g1 = 1/(1+e^{l2-l1})
        const float tt = expf(v2 - v1);
        gpair[tok*2 + 0] = 1.0f/(1.0f + tt);
        gpair[tok*2 + 1] = tt/(1.0f + tt);
        picks[tok] = (unsigned)(i1 | (i2 << 8));
    }
}

// ---------------------------------------------------------------------------
// Routing phase a: per-block (256 tokens) expert histogram (LDS atomics only).
// ---------------------------------------------------------------------------
__global__ __launch_bounds__(256)
void route_count(const unsigned int* __restrict__ picks, int* __restrict__ blockcnt)
{
    __shared__ int h[8];
    const int t = threadIdx.x;
    if (t < 8) h[t] = 0;
    __syncthreads();
    const unsigned p = picks[blockIdx.x*256 + t];
    atomicAdd(&h[p & 7], 1);
    atomicAdd(&h[(p >> 8) & 7], 1);
    __syncthreads();
    if (t < 8) blockcnt[blockIdx.x*8 + t] = h[t];
}

// ---------------------------------------------------------------------------
// Routing phase b: 128-aligned expert segment offsets, per-(block,expert)
// scatter bases, and the slot-block -> expert table. One block.
// ---------------------------------------------------------------------------
__global__ __launch_bounds__(256)
void route_offsets(const int* __restrict__ blockcnt,
                   int* __restrict__ blockbase, int* __restrict__ blkexp)
{
    __shared__ int cntS[8], eoffS[9];
    const int t = threadIdx.x;
    if (t < 8) {
        int s = 0;
        for (int b = 0; b < NRB_; b++) s += blockcnt[b*8 + t];
        cntS[t] = s;
    }
    __syncthreads();
    if (t == 0) {
        int r = 0;
        for (int e = 0; e < 8; e++) { eoffS[e] = r; r += (cntS[e] + 127) & ~127; }
        eoffS[8] = r;
    }
    __syncthreads();
    if (t < 8) {
        int r = eoffS[t];
        for (int b = 0; b < NRB_; b++) { blockbase[b*8 + t] = r; r += blockcnt[b*8 + t]; }
    }
    if (t < NBLK_) {
        const int s = t * 128;
        int e = -1;
        for (int q = 0; q < 8; q++) if (s >= eoffS[q] && s < eoffS[q+1]) e = q;
        blkexp[t] = e;
    }
}

// ---------------------------------------------------------------------------
// Routing phase c: scatter tokens to slots (LDS atomics for intra-block
// ordering; any order is numerically irrelevant, the slot<->token map is
// consistent). Writes eidx2[slot]=tok and tok2slot[tok][2].
// ---------------------------------------------------------------------------
__global__ __launch_bounds__(256)
void route_scatter(const unsigned int* __restrict__ picks,
                   const int* __restrict__ blockbase,
                   int* __restrict__ eidx2, int* __restrict__ tok2slot)
{
    __shared__ int c[8];
    const int t = threadIdx.x;
    if (t < 8) c[t] = 0;
    __syncthreads();
    const int tok = blockIdx.x*256 + t;
    const unsigned p = picks[tok];
    const int e1 = p & 7, e2 = (p >> 8) & 7;
    const int l1 = atomicAdd(&c[e1], 1);
    const int l2 = atomicAdd(&c[e2], 1);
    const int s1 = blockbase[blockIdx.x*8 + e1] + l1;
    const int s2 = blockbase[blockIdx.x*8 + e2] + l2;
    eidx2[s1] = tok;
    eidx2[s2] = tok;
    tok2slot[tok*2 + 0] = s1;
    tok2slot[tok*2 + 1] = s2;
}

// ---------------------------------------------------------------------------
// Combine: ent[tok] = g1*out2[slot1] + g2*out2[slot2] (biases already in
// out2). Writes bf16 directly. One block per token.
// ---------------------------------------------------------------------------
__global__ __launch_bounds__(256)
void combine_kernel(const float* __restrict__ out2, const float* __restrict__ gpair,
                    const int* __restrict__ tok2slot, bf16_t* __restrict__ entb)
{
    const int t = threadIdx.x;
    const long tok = blockIdx.x;
    const int s1 = tok2slot[tok*2], s2 = tok2slot[tok*2 + 1];
    const float g1 = gpair[tok*2], g2 = gpair[tok*2 + 1];
    const float4 a = ((const float4*)(out2 + (long)s1*O_))[t];
    const float4 b = ((const float4*)(out2 + (long)s2*O_))[t];
    union { bf16_t h[4]; uint2 u; } pk;
    pk.h[0] = (bf16_t)(g1*a.x + g2*b.x);
    pk.h[1] = (bf16_t)(g1*a.y + g2*b.y);
    pk.h[2] = (bf16_t)(g1*a.z + g2*b.z);
    pk.h[3] = (bf16_t)(g1*a.w + g2*b.w);
    ((uint2*)(entb + tok*O_))[t] = pk.u;
}

// ---------------------------------------------------------------------------
// Row softmax over 1024 fp32 scores; writes bf16 probs in-place into the
// first half of each row (row stride stays 1024 floats -> P lda = 2048 bf16).
// One block per row.
// ---------------------------------------------------------------------------
__global__ __launch_bounds__(256)
void softmax_rows(float* __restrict__ S)
{
    __shared__ float redA[4], redB[4];
    const int t = threadIdx.x;
    float* rowp = S + (long)blockIdx.x * 1024;
    const float4 v = ((const float4*)rowp)[t];
    const int lane = t & 63, wv = t >> 6;
    float m = fmaxf(fmaxf(v.x, v.y), fmaxf(v.z, v.w));
    for (int off = 32; off; off >>= 1) m = fmaxf(m, __shfl_down(m, off));
    if (lane == 0) redA[wv] = m;
    __syncthreads();
    m = fmaxf(fmaxf(redA[0], redA[1]), fmaxf(redA[2], redA[3]));
    const float e0 = expf(v.x - m), e1 = expf(v.y - m);
    const float e2 = expf(v.z - m), e3 = expf(v.w - m);
    float s = e0 + e1 + e2 + e3;
    for (int off = 32; off; off >>= 1) s += __shfl_down(s, off);
    if (lane == 0) redB[wv] = s;
    __syncthreads();
    const float inv = 1.0f / (redB[0] + redB[1] + redB[2] + redB[3]);
    union { bf16_t h[4]; uint2 u; } pk;
    pk.h[0] = (bf16_t)(e0*inv); pk.h[1] = (bf16_t)(e1*inv);
    pk.h[2] = (bf16_t)(e2*inv); pk.h[3] = (bf16_t)(e3*inv);
    ((uint2*)rowp)[t] = pk.u;
}

// ---------------------------------------------------------------------------
extern "C" void kernel_launch(void* const* d_in, const int* in_sizes, int n_in,
                              void* d_out, int out_size, void* d_ws, size_t ws_size,
                              hipStream_t stream)
{
    const float* x      = (const float*)d_in[0];
    const float* attn_w = (const float*)d_in[1];
    const float* gate_W = (const float*)d_in[2];
    const float* gate_b = (const float*)d_in[3];
    const float* eW1    = (const float*)d_in[4];
    const float* eb1    = (const float*)d_in[5];
    const float* eW2    = (const float*)d_in[6];
    const float* eb2    = (const float*)d_in[7];
    const float* Wq     = (const float*)d_in[8];   const float* bq = (const float*)d_in[9];
    const float* Wk     = (const float*)d_in[10];  const float* bk = (const float*)d_in[11];
    const float* Wv     = (const float*)d_in[12];  const float* bv = (const float*)d_in[13];
    const float* Wo     = (const float*)d_in[14];  const float* bo = (const float*)d_in[15];
    const float* fW1    = (const float*)d_in[16];  const float* fb1 = (const float*)d_in[17];
    const float* fW2    = (const float*)d_in[18];  const float* fb2 = (const float*)d_in[19];
    float* out = (float*)d_out;

    char* ws = (char*)d_ws;
    size_t off = 0;
    auto alloc = [&](size_t sz) -> void* {
        void* p = (void*)(ws + off);
        off += (sz + 255) & ~(size_t)255;
        return p;
    };
    // bf16 transposed weights + routing tables (persist whole call)
    bf16_t* WqT  = (bf16_t*)alloc((size_t)O_*O_*2);
    bf16_t* WkT  = (bf16_t*)alloc((size_t)O_*O_*2);
    bf16_t* WvT  = (bf16_t*)alloc((size_t)O_*O_*2);
    bf16_t* WoT  = (bf16_t*)alloc((size_t)O_*O_*2);
    bf16_t* fW1T = (bf16_t*)alloc((size_t)O_*FH_*2);
    bf16_t* fW2T = (bf16_t*)alloc((size_t)FH_*O_*2);
    bf16_t* eW1T = (bf16_t*)alloc((size_t)E_*D_*H_*2);
    bf16_t* eW2T = (bf16_t*)alloc((size_t)E_*H_*O_*2);
    unsigned int* picks = (unsigned int*)alloc((size_t)T_*4);
    float*  gpair    = (float*)alloc((size_t)T_*2*4);
    int*    blockcnt = (int*)alloc((size_t)NRB_*8*4);
    int*    blockbase= (int*)alloc((size_t)NRB_*8*4);
    int*    blkexp   = (int*)alloc((size_t)NBLK_*4);
    int*    eidx2    = (int*)alloc((size_t)SLOTS_*4);
    int*    tok2slot = (int*)alloc((size_t)T_*2*4);
    const size_t reuse0 = off;                         // ffn_h aliases from here
    float*  xaggf  = (float*)alloc((size_t)T_*D_*4);          // 32 MiB
    bf16_t* xaggb  = (bf16_t*)alloc((size_t)T_*D_*2);         // 16 MiB
    bf16_t* hidden = (bf16_t*)alloc((size_t)SLOTS_*H_*2);     // 68 MiB (slot-major)
    bf16_t* entb   = (bf16_t*)alloc((size_t)T_*O_*2);
    bf16_t* qb     = (bf16_t*)alloc((size_t)T_*O_*2);
    bf16_t* kb     = (bf16_t*)alloc((size_t)T_*O_*2);
    bf16_t* vT     = (bf16_t*)alloc((size_t)O_*T_*2); // V^T: (channel, token)
    float*  S      = (float*)alloc((size_t)16*NE_*NE_*4); // 16-bh score chunk, 64 MiB
    bf16_t* ctxb   = (bf16_t*)alloc((size_t)T_*O_*2);
    // aliases (regions dead by the time these are written):
    float*  out2  = (float*)S;                        // slot-major MoE out, 68 MiB
                                                      // over S(64)+ctxb(16); dead
                                                      // before attention writes S
    bf16_t* ffnhb = (bf16_t*)(ws + reuse0);           // 64 MiB over xaggf+xaggb+hidden[:16M]
    bf16_t* relb  = (bf16_t*)(ws + reuse0 + (size_t)80*1024*1024); // 16 MiB inside hidden

    const dim3 blk(256);

    // 1) weights -> bf16, transposed (all GEMMs become NT)
    transpose_convert<<<dim3(H_/64, D_/64, E_), blk, 0, stream>>>(eW1, eW1T, D_, H_, (long)D_*H_, (long)D_*H_);
    transpose_convert<<<dim3(O_/64, H_/64, E_), blk, 0, stream>>>(eW2, eW2T, H_, O_, (long)H_*O_, (long)H_*O_);
    transpose_convert<<<dim3(O_/64, O_/64, 1), blk, 0, stream>>>(Wq, WqT, O_, O_, 0, 0);
    transpose_convert<<<dim3(O_/64, O_/64, 1), blk, 0, stream>>>(Wk, WkT, O_, O_, 0, 0);
    transpose_convert<<<dim3(O_/64, O_/64, 1), blk, 0, stream>>>(Wv, WvT, O_, O_, 0, 0);
    transpose_convert<<<dim3(O_/64, O_/64, 1), blk, 0, stream>>>(Wo, WoT, O_, O_, 0, 0);
    transpose_convert<<<dim3(FH_/64, O_/64, 1), blk, 0, stream>>>(fW1, fW1T, O_, FH_, 0, 0);
    transpose_convert<<<dim3(O_/64, FH_/64, 1), blk, 0, stream>>>(fW2, fW2T, FH_, O_, 0, 0);

    // 2) pooling + gating + routing (no global atomics anywhere)
    (void)hipMemsetAsync(eidx2, 0, (size_t)SLOTS_*4, stream);  // pad slots -> token 0
    pool_kernel<<<dim3(T_), blk, 0, stream>>>(x, attn_w, xaggf, xaggb);
    gate_kernel<<<dim3(T_/4), blk, 0, stream>>>(xaggf, gate_W, gate_b, gpair, picks);
    route_count  <<<dim3(NRB_), blk, 0, stream>>>(picks, blockcnt);
    route_offsets<<<dim3(1),    blk, 0, stream>>>(blockcnt, blockbase, blkexp);
    route_scatter<<<dim3(NRB_), blk, 0, stream>>>(picks, blockbase, eidx2, tok2slot);

    // 3) MoE as ONE grouped GEMM pair over 128-aligned expert slot segments
    // GEMM1: hidden[slot] = relu(xagg[eidx2[slot]] @ W1[e(slot)] + b1[e])
    gemm_nt<bf16_t, false, true, true, true, true><<<dim3(NBLK_, 16, 1), blk, 0, stream>>>(
        xaggb, eW1T, hidden, eb1, eidx2, blkexp,
        D_, D_, D_, H_, 1.0f, 0, (long)D_*H_, H_, 0,0,0, 0,0,0, 0,0,0);
    // GEMM2: out2[slot] = hidden[slot] @ W2[e(slot)] + b2[e]   (slot-major)
    gemm_nt<float, false, true, false, true, false><<<dim3(NBLK_, 8, 1), blk, 0, stream>>>(
        hidden, eW2T, out2, eb2, nullptr, blkexp,
        H_, H_, H_, O_, 1.0f, 0, (long)H_*O_, O_, 0,0,0, 0,0,0, 0,0,0);
    combine_kernel<<<dim3(T_), blk, 0, stream>>>(out2, gpair, tok2slot, entb);

    // 4) QKV projections (V written transposed as (channel, token))
    gemm_nt<bf16_t, false, true, false, false, false><<<dim3(64, 8, 1), blk, 0, stream>>>(
        entb, WqT, qb, bq, nullptr, nullptr, O_, O_, O_, O_, 1.0f, 0, 0,0, 0,0,0, 0,0,0, 0,0,0);
    gemm_nt<bf16_t, false, true, false, false, false><<<dim3(64, 8, 1), blk, 0, stream>>>(
        entb, WkT, kb, bk, nullptr, nullptr, O_, O_, O_, O_, 1.0f, 0, 0,0, 0,0,0, 0,0,0, 0,0,0);
    gemm_nt<bf16_t, true, true, false, false, false><<<dim3(64, 8, 1), blk, 0, stream>>>(
        entb, WvT, vT, bv, nullptr, nullptr, O_, O_, O_, T_, 1.0f, 0, 0,0, 0,0,0, 0,0,0, 0,0,0);

    // 5) attention, 4 chunks of 16 (b,h) slabs
    const float scl = 0.088388347648318447f;  // 1/sqrt(128)
    for (int c = 0; c < 4; c++) {
        const int zb = c * 16;
        // S = scl * Q K^T   (fp32 out)
        gemm_nt<float, false, false, false, false, false><<<dim3(8, 8, 16), blk, 0, stream>>>(
            qb, kb, S, nullptr, nullptr, nullptr, HD_, O_, O_, NE_, scl, zb, 0,0,
            (long)NE_*O_, HD_, 0,   (long)NE_*O_, HD_, 0,   0, 0, (long)NE_*NE_);
        softmax_rows<<<dim3(16*NE_), blk, 0, stream>>>(S);
        // ctx = P V   (P bf16 in-place in S rows, lda=2048)
        gemm_nt<bf16_t, false, false, false, false, false><<<dim3(8, 1, 16), blk, 0, stream>>>(
            (const bf16_t*)S, vT, ctxb, nullptr, nullptr, nullptr, NE_, 2*NE_, T_, O_, 1.0f, zb, 0,0,
            0, 0, (long)2*NE_*NE_,   (long)NE_, (long)HD_*T_, 0,   (long)NE_*O_, HD_, 0);
    }

    // 6) output projection + FFN
    gemm_nt<bf16_t, false, true, false, false, false><<<dim3(64, 8, 1), blk, 0, stream>>>(
        ctxb, WoT, relb, bo, nullptr, nullptr, O_, O_, O_, O_, 1.0f, 0, 0,0, 0,0,0, 0,0,0, 0,0,0);
    gemm_nt<bf16_t, false, true, true, false, false><<<dim3(64, 32, 1), blk, 0, stream>>>(
        relb, fW1T, ffnhb, fb1, nullptr, nullptr, O_, O_, O_, FH_, 1.0f, 0, 0,0, 0,0,0, 0,0,0, 0,0,0);
    gemm_nt<float, false, true, false, false, false><<<dim3(64, 8, 1), blk, 0, stream>>>(
        ffnhb, fW2T, out, fb2, nullptr, nullptr, FH_, FH_, FH_, O_, 1.0f, 0, 0,0, 0,0,0, 0,0,0, 0,0,0);
}

// Round 3
// 1344.168 us; speedup vs baseline: 1.7621x; 1.0216x over previous
//
#include <hip/hip_runtime.h>
#include <hip/hip_bf16.h>
#include <math.h>

// ---------------------------------------------------------------------------
// EntityMoELayer: pooling+gate -> MoE(top2/8 grouped GEMM) -> FLASH attn -> FFN
// Round 5:
//  (1) flash attention: one kernel replaces QK^T-GEMM + softmax_rows + PV-GEMM
//      and the 256MiB S buffer (~770MB HBM round-trips + 12 dependent
//      launches + K=128 short-K GEMM inefficiency + half-idle PV grid).
//      LDS K/V tiles XOR-swizzled (G4: 256B rows read as b128 = 32-way
//      conflict; half_off ^= (row&7)<<3 fixes, staged via pre-swizzled
//      global source since global_load_lds writes linearly).
//  (2) gate fused into pool (xaggf buffer + gate kernel deleted).
// ---------------------------------------------------------------------------

typedef __bf16 bf16_t;
typedef __bf16 bf16x8 __attribute__((ext_vector_type(8)));
typedef float  f32x4  __attribute__((ext_vector_type(4)));

#define B_   8
#define NE_  1024
#define NO_  8
#define D_   1024
#define E_   8
#define H_   2048
#define O_   1024
#define NH_  8
#define HD_  128
#define FH_  4096
#define T_   8192          // B*NE tokens
#define NRB_ 32            // routing blocks (256 tokens each)
#define NBLK_ 136          // worst-case 128-row slot blocks (actual <= 135)
#define SLOTS_ (NBLK_*128) // 17408

__device__ __forceinline__ void gl2lds16(const bf16_t* g, bf16_t* l) {
    __builtin_amdgcn_global_load_lds(
        (const __attribute__((address_space(1))) unsigned int*)g,
        (__attribute__((address_space(3))) unsigned int*)l,
        16, 0, 0);
}

// ---------------------------------------------------------------------------
// Generic NT GEMM: C[M,N] = epi( A[M,K] * B[N,K]^T ), bf16 in, fp32 accum.
// 128x128 block tile, 4 waves (2x2 of 64x64), MFMA 16x16x32 bf16, BK=32.
// (unchanged from round 4; attention call sites removed)
// ---------------------------------------------------------------------------
template<typename OUT_T, bool TRANSC, bool BIAS, bool RELU, bool GROUPED, bool GATHER>
__global__ __launch_bounds__(256, 2)
void gemm_nt(const bf16_t* __restrict__ A, const bf16_t* __restrict__ Bm,
             OUT_T* __restrict__ C,
             const float* __restrict__ bias,
             const int* __restrict__ rowidx, const int* __restrict__ blkexp,
             int K, int lda, int ldb, int ldc, float alpha, int zbase,
             long sBe, int biasStride,
             long sAb, long sAh, long sAz,
             long sBb, long sBh, long sBz,
             long sCb, long sCh, long sCz)
{
    const int z  = blockIdx.z;
    const long bh = zbase + z;
    const long bb = bh >> 3, hh = bh & 7;
    A  += bb*sAb + hh*sAh + (long)z*sAz;
    Bm += bb*sBb + hh*sBh + (long)z*sBz;
    C  += bb*sCb + hh*sCh + (long)z*sCz;

    if (GROUPED) {
        const int ge = blkexp[blockIdx.x];
        if (ge < 0) return;               // uniform early exit (tail blocks)
        Bm += (long)ge * sBe;
        if (BIAS) bias += (long)ge * biasStride;
    }

    __shared__ __align__(16) bf16_t As[128*32];
    __shared__ __align__(16) bf16_t Bs[128*32];

    const int t    = threadIdx.x;
    const int lane = t & 63, wave = t >> 6;
    const int l16  = lane & 15, quad = lane >> 4;
    const int wm   = (wave & 1) * 64, wn = (wave >> 1) * 64;
    const int rowBase = blockIdx.x * 128;
    const int colBase = blockIdx.y * 128;

    const int lrow = lane >> 2;
    const int lch  = (lane & 3) * 8;          // halves
    long arow0, arow1;
    if (GATHER) {
        arow0 = rowidx[rowBase + wave*16 + lrow];
        arow1 = rowidx[rowBase + wave*16 + lrow + 64];
    } else {
        arow0 = rowBase + wave*16 + lrow;
        arow1 = arow0 + 64;
    }
    const bf16_t* agp0 = A  + arow0*lda + lch;
    const bf16_t* agp1 = A  + arow1*lda + lch;
    const bf16_t* bgp0 = Bm + (long)(colBase + wave*16 + lrow)*ldb + lch;
    const bf16_t* bgp1 = bgp0 + (long)64*ldb;
    bf16_t* alp0 = &As[wave*512];             // 512 halves = 16 rows
    bf16_t* alp1 = &As[(4 + wave)*512];
    bf16_t* blp0 = &Bs[wave*512];
    bf16_t* blp1 = &Bs[(4 + wave)*512];

    f32x4 acc[4][4] = {};

    for (int k0 = 0; k0 < K; k0 += 32) {
        __syncthreads();                      // prev iter's ds_reads done
        gl2lds16(agp0 + k0, alp0);
        gl2lds16(agp1 + k0, alp1);
        gl2lds16(bgp0 + k0, blp0);
        gl2lds16(bgp1 + k0, blp1);
        __syncthreads();                      // vmcnt(0) drain + barrier

        bf16x8 af[4], bfr[4];
        #pragma unroll
        for (int mi = 0; mi < 4; mi++)
            af[mi] = *(const bf16x8*)&As[(wm + mi*16 + l16)*32 + quad*8];
        #pragma unroll
        for (int ni = 0; ni < 4; ni++)
            bfr[ni] = *(const bf16x8*)&Bs[(wn + ni*16 + l16)*32 + quad*8];
        #pragma unroll
        for (int mi = 0; mi < 4; mi++)
            #pragma unroll
            for (int ni = 0; ni < 4; ni++)
                acc[mi][ni] = __builtin_amdgcn_mfma_f32_16x16x32_bf16(
                                  af[mi], bfr[ni], acc[mi][ni], 0, 0, 0);
    }

    // epilogue: D[row = quad*4+r][col = l16] per 16x16 tile (m89-verified map)
    #pragma unroll
    for (int mi = 0; mi < 4; mi++) {
        #pragma unroll
        for (int ni = 0; ni < 4; ni++) {
            const int col = colBase + wn + ni*16 + l16;
            float bv = 0.0f;
            if (BIAS) bv = bias[col];
            #pragma unroll
            for (int rr = 0; rr < 4; rr++) {
                const int row = rowBase + wm + mi*16 + quad*4 + rr;
                float v = acc[mi][ni][rr] * alpha;
                if (BIAS)   v += bv;
                if (RELU)   v = fmaxf(v, 0.0f);
                if (TRANSC) C[(long)col*ldc + row] = (OUT_T)v;  // C^T (for V)
                else        C[(long)row*ldc + col] = (OUT_T)v;
            }
        }
    }
}

// ---------------------------------------------------------------------------
// Flash attention: one block per (q-block of 128 rows, bh). 4 waves; wave w
// owns q-rows [w*32, w*32+32) -> row softmax stats never cross waves.
// LDS: KP[128][128] bf16 (K-tile, aliased as P-tile after S compute) +
//      Vs[128][128] bf16 (V^T tile [d][kv], staged from vT). 64 KiB.
// Swizzle: half_off_in_row ^= (row&7)<<3  (== byte ^ (row&7)<<4; G4 fix for
// 256B-row b128 reads). global_load_lds writes linear -> swizzle applied by
// permuting the per-lane GLOBAL source chunk (m173 pattern).
// ---------------------------------------------------------------------------
__global__ __launch_bounds__(256, 2)
void flash_attn(const bf16_t* __restrict__ qg, const bf16_t* __restrict__ kg,
                const bf16_t* __restrict__ vTg, bf16_t* __restrict__ ctx)
{
    const int bh = blockIdx.z;
    const long bb = bh >> 3, hh = bh & 7;
    const int qb0 = blockIdx.x * 128;

    __shared__ __align__(16) bf16_t KP[128*128];  // K-tile [kv][d] -> P-tile [q][kv]
    __shared__ __align__(16) bf16_t Vs[128*128];  // V^T-tile [d][kv]

    const int t = threadIdx.x;
    const int lane = t & 63, w = t >> 6;
    const int l16 = lane & 15, quad = lane >> 4;
    const float scl = 0.088388347648318447f;      // 1/sqrt(128)

    // Q fragments (A-operand): rows w*32+mi*16+l16, d = kk*32+quad*8
    bf16x8 qf[2][4];
    {
        const bf16_t* q0 = qg + ((long)bb*1024 + qb0 + w*32 + l16)*O_ + hh*128 + quad*8;
        #pragma unroll
        for (int mi = 0; mi < 2; mi++)
            #pragma unroll
            for (int kk = 0; kk < 4; kk++)
                qf[mi][kk] = *(const bf16x8*)(q0 + (long)mi*16*O_ + kk*32);
    }

    f32x4 o[2][8] = {};                // [mi][dn], rows as C-layout
    float mrow[2][4], lrow[2][4];
    #pragma unroll
    for (int mi = 0; mi < 2; mi++)
        #pragma unroll
        for (int rr = 0; rr < 4; rr++) { mrow[mi][rr] = -3.4e38f; lrow[mi][rr] = 0.0f; }

    // staging lane map (per issue of 4 rows): rloc = i*4 + (lane>>4),
    // physical chunk = lane&15, source chunk = phys ^ (absrow&7).
    const int srloc = lane >> 4;       // 0..3
    const int spc   = lane & 15;       // 16B chunk

    for (int kt = 0; kt < 8; kt++) {
        const int kv0 = kt * 128;
        __syncthreads();               // all waves done with KP(P)/Vs of prev tile

        // stage K rows [w*32, +32) and V^T d-rows [w*32, +32)
        #pragma unroll
        for (int i = 0; i < 8; i++) {
            const int r = w*32 + i*4 + srloc;              // abs row in tile
            const int sc = spc ^ (r & 7);
            gl2lds16(kg + ((long)bb*1024 + kv0 + r)*O_ + hh*128 + sc*8,
                     &KP[(w*32 + i*4)*128]);
            gl2lds16(vTg + ((long)hh*128 + r)*T_ + bb*1024 + kv0 + sc*8,
                     &Vs[(w*32 + i*4)*128]);
        }
        __syncthreads();               // vmcnt(0) drain + barrier: tiles ready

        // S = Q K^T for this wave's 32 rows x 128 kv cols
        f32x4 sa[2][8] = {};
        #pragma unroll
        for (int kk = 0; kk < 4; kk++) {
            bf16x8 bf_[8];
            #pragma unroll
            for (int ni = 0; ni < 8; ni++) {
                const int n = ni*16 + l16;
                bf_[ni] = *(const bf16x8*)&KP[n*128 + ((kk*32 + quad*8) ^ ((n & 7) << 3))];
            }
            #pragma unroll
            for (int mi = 0; mi < 2; mi++)
                #pragma unroll
                for (int ni = 0; ni < 8; ni++)
                    sa[mi][ni] = __builtin_amdgcn_mfma_f32_16x16x32_bf16(
                                     qf[mi][kk], bf_[ni], sa[mi][ni], 0, 0, 0);
        }

        // online softmax stats (rows local to wave; reduce over ni + 16 lanes)
        float f2[2][4];
        #pragma unroll
        for (int mi = 0; mi < 2; mi++) {
            #pragma unroll
            for (int rr = 0; rr < 4; rr++) {
                float rm = -3.4e38f;
                #pragma unroll
                for (int ni = 0; ni < 8; ni++) rm = fmaxf(rm, sa[mi][ni][rr]);
                rm *= scl;                                  // scl > 0
                #pragma unroll
                for (int off = 1; off < 16; off <<= 1)
                    rm = fmaxf(rm, __shfl_xor(rm, off));
                const float mn = fmaxf(mrow[mi][rr], rm);
                const float f = expf(mrow[mi][rr] - mn);    // 0 on first tile
                mrow[mi][rr] = mn; f2[mi][rr] = f;
                float rs = 0.0f;
                #pragma unroll
                for (int ni = 0; ni < 8; ni++) {
                    const float p = expf(sa[mi][ni][rr]*scl - mn);
                    sa[mi][ni][rr] = p;
                    rs += p;
                }
                #pragma unroll
                for (int off = 1; off < 16; off <<= 1)
                    rs += __shfl_xor(rs, off);
                lrow[mi][rr] = lrow[mi][rr]*f + rs;
            }
        }
        #pragma unroll
        for (int mi = 0; mi < 2; mi++)
            #pragma unroll
            for (int dn = 0; dn < 8; dn++)
                #pragma unroll
                for (int rr = 0; rr < 4; rr++)
                    o[mi][dn][rr] *= f2[mi][rr];

        __syncthreads();               // all waves done READING KP before P write

        // P -> bf16 into KP (swizzled); wave writes only its own 32 q-rows
        #pragma unroll
        for (int mi = 0; mi < 2; mi++)
            #pragma unroll
            for (int ni = 0; ni < 8; ni++)
                #pragma unroll
                for (int rr = 0; rr < 4; rr++) {
                    const int qr  = w*32 + mi*16 + quad*4 + rr;
                    const int col = ni*16 + l16;
                    KP[qr*128 + (col ^ ((qr & 7) << 3))] = (bf16_t)sa[mi][ni][rr];
                }

        // O += P V  (A = own P rows from KP, B = Vs d-rows; lgkmcnt orders
        // same-wave ds_write->ds_read, no barrier needed)
        #pragma unroll
        for (int kkv = 0; kkv < 4; kkv++) {
            bf16x8 pa[2], vb[8];
            #pragma unroll
            for (int pmi = 0; pmi < 2; pmi++) {
                const int qr2 = w*32 + pmi*16 + l16;
                pa[pmi] = *(const bf16x8*)&KP[qr2*128 + ((kkv*32 + quad*8) ^ ((qr2 & 7) << 3))];
            }
            #pragma unroll
            for (int dn = 0; dn < 8; dn++) {
                const int d = dn*16 + l16;
                vb[dn] = *(const bf16x8*)&Vs[d*128 + ((kkv*32 + quad*8) ^ ((d & 7) << 3))];
            }
            #pragma unroll
            for (int pmi = 0; pmi < 2; pmi++)
                #pragma unroll
                for (int dn = 0; dn < 8; dn++)
                    o[pmi][dn] = __builtin_amdgcn_mfma_f32_16x16x32_bf16(
                                     pa[pmi], vb[dn], o[pmi][dn], 0, 0, 0);
        }
    }

    // epilogue: O /= l, write ctx rows (C-layout map)
    #pragma unroll
    for (int mi = 0; mi < 2; mi++) {
        #pragma unroll
        for (int rr = 0; rr < 4; rr++) {
            const float inv = 1.0f / lrow[mi][rr];
            const long row = (long)bb*1024 + qb0 + w*32 + mi*16 + quad*4 + rr;
            #pragma unroll
            for (int dn = 0; dn < 8; dn++)
                ctx[row*O_ + hh*128 + dn*16 + l16] = (bf16_t)(o[mi][dn][rr] * inv);
        }
    }
}

// ---------------------------------------------------------------------------
// fp32 (R x C) -> bf16 transposed (C x R), 64x64 LDS tiles, batched (grid.z)
// ---------------------------------------------------------------------------
__global__ __launch_bounds__(256)
void transpose_convert(const float* __restrict__ in, bf16_t* __restrict__ out,
                       int R, int C, long inStride, long outStride)
{
    __shared__ float tl[64][65];
    const int t = threadIdx.x;
    const float* src = in  + (long)blockIdx.z * inStride;
    bf16_t*      dst = out + (long)blockIdx.z * outStride;
    const int c0 = blockIdx.x * 64, r0 = blockIdx.y * 64;
    #pragma unroll
    for (int i = 0; i < 16; i++) {
        const int idx = t + i*256, r = idx >> 6, c = idx & 63;
        tl[r][c] = src[(long)(r0 + r)*C + c0 + c];
    }
    __syncthreads();
    #pragma unroll
    for (int i = 0; i < 16; i++) {
        const int idx = t + i*256, rT = idx >> 6, cT = idx & 63;
        dst[(long)(c0 + rT)*R + r0 + cT] = (bf16_t)tl[cT][rT];
    }
}

// ---------------------------------------------------------------------------
// Fused pooling + gate: per token (b,n): softmax over NO=8 object logits,
// weighted sum -> x_agg (bf16 out only); then gate logits (x_agg @ gate_W+b),
// top-2 (tie -> lower index), renormalized gates -> gpair, picks.
// One block per token.
// ---------------------------------------------------------------------------
__global__ __launch_bounds__(256)
void pool_gate_kernel(const float* __restrict__ x, const float* __restrict__ attn_w,
                      const float* __restrict__ gate_W, const float* __restrict__ gate_b,
                      bf16_t* __restrict__ xaggb, float* __restrict__ gpair,
                      unsigned int* __restrict__ picks)
{
    __shared__ float xs[8192];      // 8 objects x 1024 dims
    __shared__ float red[32];
    const int t = threadIdx.x;
    const long tok = blockIdx.x;
    const float4* src = (const float4*)(x + tok*8192);
    float4* xs4 = (float4*)xs;
    #pragma unroll
    for (int i = 0; i < 8; i++) xs4[t + i*256] = src[t + i*256];
    float wreg[4];
    #pragma unroll
    for (int j = 0; j < 4; j++) wreg[j] = attn_w[t + j*256];
    __syncthreads();

    float part[8];
    #pragma unroll
    for (int o = 0; o < 8; o++) {
        float p = 0.0f;
        #pragma unroll
        for (int j = 0; j < 4; j++) p += xs[o*1024 + t + j*256] * wreg[j];
        part[o] = p;
    }
    const int lane = t & 63, wv = t >> 6;
    #pragma unroll
    for (int o = 0; o < 8; o++) {
        float v = part[o];
        for (int off = 32; off; off >>= 1) v += __shfl_down(v, off);
        if (lane == 0) red[o*4 + wv] = v;
    }
    __syncthreads();
    float lg[8], mx = -3.4e38f;
    #pragma unroll
    for (int o = 0; o < 8; o++) {
        lg[o] = red[o*4] + red[o*4+1] + red[o*4+2] + red[o*4+3];
        mx = fmaxf(mx, lg[o]);
    }
    float ssum = 0.0f;
    #pragma unroll
    for (int o = 0; o < 8; o++) { lg[o] = expf(lg[o] - mx); ssum += lg[o]; }
    const float inv = 1.0f / ssum;

    // x_agg dims for this thread + gate partials
    float gl[8] = {0,0,0,0,0,0,0,0};
    #pragma unroll
    for (int j = 0; j < 4; j++) {
        const int d = t + j*256;
        float a = 0.0f;
        #pragma unroll
        for (int o = 0; o < 8; o++) a += lg[o] * xs[o*1024 + d];
        a *= inv;
        xaggb[tok*1024 + d] = (bf16_t)a;
        const float4 w0 = *(const float4*)(gate_W + (long)d*8);
        const float4 w1 = *(const float4*)(gate_W + (long)d*8 + 4);
        gl[0] += a*w0.x; gl[1] += a*w0.y; gl[2] += a*w0.z; gl[3] += a*w0.w;
        gl[4] += a*w1.x; gl[5] += a*w1.y; gl[6] += a*w1.z; gl[7] += a*w1.w;
    }
    __syncthreads();                   // red[] reuse
    #pragma unroll
    for (int e = 0; e < 8; e++) {
        float v = gl[e];
        for (int off = 32; off; off >>= 1) v += __shfl_down(v, off);
        if (lane == 0) red[e*4 + wv] = v;
    }
    __syncthreads();
    if (t == 0) {
        float l[8];
        #pragma unroll
        for (int e = 0; e < 8; e++)
            l[e] = red[e*4] + red[e*4+1] + red[e*4+2] + red[e*4+3] + gate_b[e];
        int i1 = 0; float v1 = l[0];
        #pragma unroll
        for (int e = 1; e < 8; e++) if (l[e] > v1) { v1 = l[e]; i1 = e; }
        int i2 = -1; float v2 = -3.4e38f;
        #pragma unroll
        for (int e = 0; e < 8; e++) if (e != i1 && l[e] > v2) { v2 = l[e]; i2 = e; }
        const float tt = expf(v2 - v1);
        gpair[tok*2 + 0] = 1.0f/(1.0f + tt);
        gpair[tok*2 + 1] = tt/(1.0f + tt);
        picks[tok] = (unsigned)(i1 | (i2 << 8));
    }
}

// ---------------------------------------------------------------------------
// Routing phase a: per-block (256 tokens) expert histogram (LDS atomics only).
// ---------------------------------------------------------------------------
__global__ __launch_bounds__(256)
void route_count(const unsigned int* __restrict__ picks, int* __restrict__ blockcnt)
{
    __shared__ int h[8];
    const int t = threadIdx.x;
    if (t < 8) h[t] = 0;
    __syncthreads();
    const unsigned p = picks[blockIdx.x*256 + t];
    atomicAdd(&h[p & 7], 1);
    atomicAdd(&h[(p >> 8) & 7], 1);
    __syncthreads();
    if (t < 8) blockcnt[blockIdx.x*8 + t] = h[t];
}

// ---------------------------------------------------------------------------
// Routing phase b: 128-aligned expert segment offsets, per-(block,expert)
// scatter bases, and the slot-block -> expert table. One block.
// ---------------------------------------------------------------------------
__global__ __launch_bounds__(256)
void route_offsets(const int* __restrict__ blockcnt,
                   int* __restrict__ blockbase, int* __restrict__ blkexp)
{
    __shared__ int cntS[8], eoffS[9];
    const int t = threadIdx.x;
    if (t < 8) {
        int s = 0;
        for (int b = 0; b < NRB_; b++) s += blockcnt[b*8 + t];
        cntS[t] = s;
    }
    __syncthreads();
    if (t == 0) {
        int r = 0;
        for (int e = 0; e < 8; e++) { eoffS[e] = r; r += (cntS[e] + 127) & ~127; }
        eoffS[8] = r;
    }
    __syncthreads();
    if (t < 8) {
        int r = eoffS[t];
        for (int b = 0; b < NRB_; b++) { blockbase[b*8 + t] = r; r += blockcnt[b*8 + t]; }
    }
    if (t < NBLK_) {
        const int s = t * 128;
        int e = -1;
        for (int q = 0; q < 8; q++) if (s >= eoffS[q] && s < eoffS[q+1]) e = q;
        blkexp[t] = e;
    }
}

// ---------------------------------------------------------------------------
// Routing phase c: scatter tokens to slots (LDS atomics for intra-block
// ordering; slot order numerically irrelevant). eidx2[slot]=tok, tok2slot.
// ---------------------------------------------------------------------------
__global__ __launch_bounds__(256)
void route_scatter(const unsigned int* __restrict__ picks,
                   const int* __restrict__ blockbase,
                   int* __restrict__ eidx2, int* __restrict__ tok2slot)
{
    __shared__ int c[8];
    const int t = threadIdx.x;
    if (t < 8) c[t] = 0;
    __syncthreads();
    const int tok = blockIdx.x*256 + t;
    const unsigned p = picks[tok];
    const int e1 = p & 7, e2 = (p >> 8) & 7;
    const int l1 = atomicAdd(&c[e1], 1);
    const int l2 = atomicAdd(&c[e2], 1);
    const int s1 = blockbase[blockIdx.x*8 + e1] + l1;
    const int s2 = blockbase[blockIdx.x*8 + e2] + l2;
    eidx2[s1] = tok;
    eidx2[s2] = tok;
    tok2slot[tok*2 + 0] = s1;
    tok2slot[tok*2 + 1] = s2;
}

// ---------------------------------------------------------------------------
// Combine: ent[tok] = g1*out2[slot1] + g2*out2[slot2] (biases already in
// out2). Writes bf16 directly. One block per token.
// ---------------------------------------------------------------------------
__global__ __launch_bounds__(256)
void combine_kernel(const float* __restrict__ out2, const float* __restrict__ gpair,
                    const int* __restrict__ tok2slot, bf16_t* __restrict__ entb)
{
    const int t = threadIdx.x;
    const long tok = blockIdx.x;
    const int s1 = tok2slot[tok*2], s2 = tok2slot[tok*2 + 1];
    const float g1 = gpair[tok*2], g2 = gpair[tok*2 + 1];
    const float4 a = ((const float4*)(out2 + (long)s1*O_))[t];
    const float4 b = ((const float4*)(out2 + (long)s2*O_))[t];
    union { bf16_t h[4]; uint2 u; } pk;
    pk.h[0] = (bf16_t)(g1*a.x + g2*b.x);
    pk.h[1] = (bf16_t)(g1*a.y + g2*b.y);
    pk.h[2] = (bf16_t)(g1*a.z + g2*b.z);
    pk.h[3] = (bf16_t)(g1*a.w + g2*b.w);
    ((uint2*)(entb + tok*O_))[t] = pk.u;
}

// ---------------------------------------------------------------------------
extern "C" void kernel_launch(void* const* d_in, const int* in_sizes, int n_in,
                              void* d_out, int out_size, void* d_ws, size_t ws_size,
                              hipStream_t stream)
{
    const float* x      = (const float*)d_in[0];
    const float* attn_w = (const float*)d_in[1];
    const float* gate_W = (const float*)d_in[2];
    const float* gate_b = (const float*)d_in[3];
    const float* eW1    = (const float*)d_in[4];
    const float* eb1    = (const float*)d_in[5];
    const float* eW2    = (const float*)d_in[6];
    const float* eb2    = (const float*)d_in[7];
    const float* Wq     = (const float*)d_in[8];   const float* bq = (const float*)d_in[9];
    const float* Wk     = (const float*)d_in[10];  const float* bk = (const float*)d_in[11];
    const float* Wv     = (const float*)d_in[12];  const float* bv = (const float*)d_in[13];
    const float* Wo     = (const float*)d_in[14];  const float* bo = (const float*)d_in[15];
    const float* fW1    = (const float*)d_in[16];  const float* fb1 = (const float*)d_in[17];
    const float* fW2    = (const float*)d_in[18];  const float* fb2 = (const float*)d_in[19];
    float* out = (float*)d_out;

    char* ws = (char*)d_ws;
    size_t off = 0;
    auto alloc = [&](size_t sz) -> void* {
        void* p = (void*)(ws + off);
        off += (sz + 255) & ~(size_t)255;
        return p;
    };
    // bf16 transposed weights + routing tables (persist whole call)
    bf16_t* WqT  = (bf16_t*)alloc((size_t)O_*O_*2);
    bf16_t* WkT  = (bf16_t*)alloc((size_t)O_*O_*2);
    bf16_t* WvT  = (bf16_t*)alloc((size_t)O_*O_*2);
    bf16_t* WoT  = (bf16_t*)alloc((size_t)O_*O_*2);
    bf16_t* fW1T = (bf16_t*)alloc((size_t)O_*FH_*2);
    bf16_t* fW2T = (bf16_t*)alloc((size_t)FH_*O_*2);
    bf16_t* eW1T = (bf16_t*)alloc((size_t)E_*D_*H_*2);
    bf16_t* eW2T = (bf16_t*)alloc((size_t)E_*H_*O_*2);
    unsigned int* picks = (unsigned int*)alloc((size_t)T_*4);
    float*  gpair    = (float*)alloc((size_t)T_*2*4);
    int*    blockcnt = (int*)alloc((size_t)NRB_*8*4);
    int*    blockbase= (int*)alloc((size_t)NRB_*8*4);
    int*    blkexp   = (int*)alloc((size_t)NBLK_*4);
    int*    eidx2    = (int*)alloc((size_t)SLOTS_*4);
    int*    tok2slot = (int*)alloc((size_t)T_*2*4);
    const size_t reuse0 = off;                         // aliases from here
    bf16_t* xaggb  = (bf16_t*)alloc((size_t)T_*D_*2);         // 16 MiB
    bf16_t* hidden = (bf16_t*)alloc((size_t)SLOTS_*H_*2);     // 68 MiB (slot-major)
    float*  out2   = (float*)alloc((size_t)SLOTS_*O_*4);      // 68 MiB (slot-major)
    bf16_t* entb   = (bf16_t*)alloc((size_t)T_*O_*2);
    bf16_t* qb     = (bf16_t*)alloc((size_t)T_*O_*2);
    bf16_t* kb     = (bf16_t*)alloc((size_t)T_*O_*2);
    bf16_t* vT     = (bf16_t*)alloc((size_t)O_*T_*2); // V^T: (channel, token)
    bf16_t* ctxb   = (bf16_t*)alloc((size_t)T_*O_*2);
    // aliases (regions dead by the time these are written):
    bf16_t* ffnhb = (bf16_t*)(ws + reuse0);           // 64 MiB over xaggb+hidden[:48M]
    bf16_t* relb  = (bf16_t*)(ws + reuse0 + (size_t)64*1024*1024); // 16 MiB in hidden

    const dim3 blk(256);

    // 1) weights -> bf16, transposed (all GEMMs become NT)
    transpose_convert<<<dim3(H_/64, D_/64, E_), blk, 0, stream>>>(eW1, eW1T, D_, H_, (long)D_*H_, (long)D_*H_);
    transpose_convert<<<dim3(O_/64, H_/64, E_), blk, 0, stream>>>(eW2, eW2T, H_, O_, (long)H_*O_, (long)H_*O_);
    transpose_convert<<<dim3(O_/64, O_/64, 1), blk, 0, stream>>>(Wq, WqT, O_, O_, 0, 0);
    transpose_convert<<<dim3(O_/64, O_/64, 1), blk, 0, stream>>>(Wk, WkT, O_, O_, 0, 0);
    transpose_convert<<<dim3(O_/64, O_/64, 1), blk, 0, stream>>>(Wv, WvT, O_, O_, 0, 0);
    transpose_convert<<<dim3(O_/64, O_/64, 1), blk, 0, stream>>>(Wo, WoT, O_, O_, 0, 0);
    transpose_convert<<<dim3(FH_/64, O_/64, 1), blk, 0, stream>>>(fW1, fW1T, O_, FH_, 0, 0);
    transpose_convert<<<dim3(O_/64, FH_/64, 1), blk, 0, stream>>>(fW2, fW2T, FH_, O_, 0, 0);

    // 2) fused pooling+gating, then routing (LDS atomics only)
    (void)hipMemsetAsync(eidx2, 0, (size_t)SLOTS_*4, stream);  // pad slots -> token 0
    pool_gate_kernel<<<dim3(T_), blk, 0, stream>>>(x, attn_w, gate_W, gate_b,
                                                   xaggb, gpair, picks);
    route_count  <<<dim3(NRB_), blk, 0, stream>>>(picks, blockcnt);
    route_offsets<<<dim3(1),    blk, 0, stream>>>(blockcnt, blockbase, blkexp);
    route_scatter<<<dim3(NRB_), blk, 0, stream>>>(picks, blockbase, eidx2, tok2slot);

    // 3) MoE as ONE grouped GEMM pair over 128-aligned expert slot segments
    gemm_nt<bf16_t, false, true, true, true, true><<<dim3(NBLK_, 16, 1), blk, 0, stream>>>(
        xaggb, eW1T, hidden, eb1, eidx2, blkexp,
        D_, D_, D_, H_, 1.0f, 0, (long)D_*H_, H_, 0,0,0, 0,0,0, 0,0,0);
    gemm_nt<float, false, true, false, true, false><<<dim3(NBLK_, 8, 1), blk, 0, stream>>>(
        hidden, eW2T, out2, eb2, nullptr, blkexp,
        H_, H_, H_, O_, 1.0f, 0, (long)H_*O_, O_, 0,0,0, 0,0,0, 0,0,0);
    combine_kernel<<<dim3(T_), blk, 0, stream>>>(out2, gpair, tok2slot, entb);

    // 4) QKV projections (V written transposed as (channel, token))
    gemm_nt<bf16_t, false, true, false, false, false><<<dim3(64, 8, 1), blk, 0, stream>>>(
        entb, WqT, qb, bq, nullptr, nullptr, O_, O_, O_, O_, 1.0f, 0, 0,0, 0,0,0, 0,0,0, 0,0,0);
    gemm_nt<bf16_t, false, true, false, false, false><<<dim3(64, 8, 1), blk, 0, stream>>>(
        entb, WkT, kb, bk, nullptr, nullptr, O_, O_, O_, O_, 1.0f, 0, 0,0, 0,0,0, 0,0,0, 0,0,0);
    gemm_nt<bf16_t, true, true, false, false, false><<<dim3(64, 8, 1), blk, 0, stream>>>(
        entb, WvT, vT, bv, nullptr, nullptr, O_, O_, O_, T_, 1.0f, 0, 0,0, 0,0,0, 0,0,0, 0,0,0);

    // 5) flash attention (replaces QK^T GEMM + softmax + PV GEMM + S buffer)
    flash_attn<<<dim3(8, 1, 64), blk, 0, stream>>>(qb, kb, vT, ctxb);

    // 6) output projection + FFN
    gemm_nt<bf16_t, false, true, false, false, false><<<dim3(64, 8, 1), blk, 0, stream>>>(
        ctxb, WoT, relb, bo, nullptr, nullptr, O_, O_, O_, O_, 1.0f, 0, 0,0, 0,0,0, 0,0,0, 0,0,0);
    gemm_nt<bf16_t, false, true, true, false, false><<<dim3(64, 32, 1), blk, 0, stream>>>(
        relb, fW1T, ffnhb, fb1, nullptr, nullptr, O_, O_, O_, FH_, 1.0f, 0, 0,0, 0,0,0, 0,0,0, 0,0,0);
    gemm_nt<float, false, true, false, false, false><<<dim3(64, 8, 1), blk, 0, stream>>>(
        ffnhb, fW2T, out, fb2, nullptr, nullptr, FH_, FH_, FH_, O_, 1.0f, 0, 0,0, 0,0,0, 0,0,0, 0,0,0);
}